// Round 18
// baseline (29.595 us; speedup 1.0000x reference)
//
#include <hip/hip_runtime.h>

#define WINDOW 11
#define H 512
#define W 512
#define OH 502            // H - WINDOW + 1
#define OW 502
#define NCH 3
#define BATCH 8
#define RSTRIPE 11        // one unrolled 11-pass; FIFO slot = unroll index
#define NSTRIPES 46       // 45 x 11 rows + 1 x 7 live rows (masked)
#define NGRP 5            // col groups: 4 x 118 outputs + 1 x 30 (float2 lanes)
#define GRPW 118          // output cols per full group (64 lanes * 2 - 10 halo)
#define WAVES_PER_IMG (NSTRIPES * NGRP)                 // 230
#define NWAVES (BATCH * NCH * WAVES_PER_IMG)            // 5520
#define WAVES_PER_BATCH (NCH * WAVES_PER_IMG)           // 690
#define NXCD 8
#define CHUNK (NWAVES / NXCD)                           // 690 = one batch per XCD

#define NPIX_PER_BATCH (3.0f * 502.0f * 502.0f)   // 756012

// packed 2xf32: elementwise ops compile to v_pk_{add,mul,fma}_f32 on gfx950
typedef float v2f __attribute__((ext_vector_type(2)));

// ---- gfx9 DPP inclusive wave scan (64 lanes), VALU-pipe only, 4-cyc hops ----
template <int CTRL, int RM>
__device__ __forceinline__ float scan_step(float x) {
    int s = __builtin_amdgcn_update_dpp(0, __builtin_bit_cast(int, x),
                                        CTRL, RM, 0xf, false);
    return x + __builtin_bit_cast(float, s);
}
__device__ __forceinline__ float wave_iscan(float x) {
    x = scan_step<0x111, 0xf>(x);   // row_shr:1
    x = scan_step<0x112, 0xf>(x);   // row_shr:2
    x = scan_step<0x114, 0xf>(x);   // row_shr:4
    x = scan_step<0x118, 0xf>(x);   // row_shr:8
    x = scan_step<0x142, 0xa>(x);   // row_bcast:15 -> rows 1,3
    x = scan_step<0x143, 0xc>(x);   // row_bcast:31 -> rows 2,3
    return x;
}

__global__ __launch_bounds__(64) void ssim_main(const float* __restrict__ x,
                                                const float* __restrict__ y,
                                                float* __restrict__ partials) {
    const int lane = threadIdx.x & 63;

    // XCD-chunked bijective swizzle: one batch (3 images) per XCD -> halo
    // rows shared between stripes re-read XCD-L2-locally.
    const int wg    = blockIdx.x;               // 0..5519, round-robins XCDs
    const int w_lin = (wg % NXCD) * CHUNK + wg / NXCD;

    const int img = w_lin / WAVES_PER_IMG;      // b*NCH + c
    const int rem = w_lin % WAVES_PER_IMG;
    const int grp = rem / NSTRIPES;
    const int rs  = rem % NSTRIPES;             // stripe minor -> L2-contiguous

    const int i0 = rs * RSTRIPE;
    const int i1 = min(i0 + RSTRIPE, OH);       // 11 rows; stripe 45: 7 live
    const int cstart = grp * GRPW;              // first staged/output col
    const int outw   = min(GRPW, OW - cstart);  // 118 or 30
    // clamped column pair: out-of-range lanes read real (unused) data
    const int c0 = min(cstart + 2 * lane, W - 2);
    const bool tapActive = (2 * lane < outw);

    const float* __restrict__ xc = x + (size_t)img * H * W + c0;
    const float* __restrict__ yc = y + (size_t)img * H * W + c0;

    // --- 11-row register FIFO: each input row loaded exactly ONCE ---
    v2f fx[11], fy[11];
    // per-column-pair sums {col 2l, col 2l+1}: x, y, x2+y2, xy
    v2f Qx = 0.f, Qy = 0.f, Qz = 0.f, Qw = 0.f;
#pragma unroll
    for (int r = 0; r < WINDOW; ++r) {
        v2f a = *(const v2f*)(xc + (size_t)(i0 + r) * W);
        v2f b = *(const v2f*)(yc + (size_t)(i0 + r) * W);
        fx[r] = a; fy[r] = b;
        Qx += a;
        Qy += b;
        Qz += a * a + b * b;
        Qw += a * b;
    }

    // depth-2 incoming-row pipeline (rows i+11, i+12 in flight)
    v2f nxA, nyA, nxB, nyB;
#define LDROW(j, nx, ny) do {                                        \
        int jc_ = min((j), H - 1);                                   \
        nx = *(const v2f*)(xc + (size_t)jc_ * W);                    \
        ny = *(const v2f*)(yc + (size_t)jc_ * W);                    \
    } while (0)

    // packed slide: old row from FIFO slot u, new row from (nx, ny)
#define SLIDE(u, nx, ny) do {                                         \
        Qx += nx - fx[u];                                             \
        Qy += ny - fy[u];                                             \
        Qz += nx * nx + ny * ny - fx[u] * fx[u] - fy[u] * fy[u];      \
        Qw += nx * ny - fx[u] * fy[u];                                \
        fx[u] = nx; fy[u] = ny;                                       \
    } while (0)

    float acc = 0.f;

    // window sums via DPP scan over pair-totals T, then lane+5 fetches:
    //   We[l] = (S[l+5]-q1[l+5]) - (S[l]-T[l])    (cols 2l..2l+10)
    //   Wo[l] =  S[l+5] - S[l] + q1[l]            (cols 2l+1..2l+11)
#define COMPUTE(rowActive) do {                                               \
        float Tx = Qx.x + Qx.y, Ty = Qy.x + Qy.y;                             \
        float Tz = Qz.x + Qz.y, Tw = Qw.x + Qw.y;                             \
        float Sx = wave_iscan(Tx), Sy = wave_iscan(Ty);                       \
        float Sz = wave_iscan(Tz), Sw = wave_iscan(Tw);                       \
        int src = lane + 5;                                                   \
        float Ax = __shfl(Sx, src, 64), Ay = __shfl(Sy, src, 64);             \
        float Az = __shfl(Sz, src, 64), Aw = __shfl(Sw, src, 64);             \
        float Bx = __shfl(Qx.y, src, 64), By = __shfl(Qy.y, src, 64);         \
        float Bz = __shfl(Qz.y, src, 64), Bw = __shfl(Qw.y, src, 64);         \
        v2f Wx = {Ax - Bx - Sx + Tx, Ax - Sx + Qx.y};                         \
        v2f Wy = {Ay - By - Sy + Ty, Ay - Sy + Qy.y};                         \
        v2f Wz = {Az - Bz - Sz + Tz, Az - Sz + Qz.y};                         \
        v2f Ww = {Aw - Bw - Sw + Tw, Aw - Sw + Qw.y};                         \
        /* packed SSIM for the {even, odd} window pair */                     \
        v2f mx  = Wx * (1.0f / 121.0f);                                       \
        v2f my  = Wy * (1.0f / 121.0f);                                       \
        v2f mxy = mx * my;                                                    \
        v2f m2  = mx * mx + my * my;                                          \
        v2f cov = (Ww - 121.0f * mxy) * (1.0f / 120.0f);                      \
        v2f vv  = (Wz - 121.0f * m2)  * (1.0f / 120.0f);                      \
        v2f num = (2.0f * mxy + 1e-4f) * (2.0f * cov + 9e-4f);                \
        v2f den = (m2 + 1e-4f) * (vv + 9e-4f);                                \
        float r = num.x * __builtin_amdgcn_rcpf(den.x)                        \
                + num.y * __builtin_amdgcn_rcpf(den.y);                       \
        acc += (tapActive & (rowActive)) ? r : 0.f;                           \
    } while (0)

    // --- single unrolled 11-pass; incoming rows pipelined 2 deep ---
    LDROW(i0 + WINDOW,     nxA, nyA);     // row i0+11 -> A
    LDROW(i0 + WINDOW + 1, nxB, nyB);     // row i0+12 -> B
#pragma unroll
    for (int u = 0; u < 11; ++u) {
        const int i = i0 + u;
        COMPUTE(i < i1);                  // window sums + SSIM for row i
        if ((u & 1) == 0) {               // static alternation over the unroll
            SLIDE(u, nxA, nyA);           // consume A (row i+11)
            LDROW(i + WINDOW + 2, nxA, nyA);   // refill A (row i+13, clamped)
        } else {
            SLIDE(u, nxB, nyB);           // consume B (row i+11)
            LDROW(i + WINDOW + 2, nxB, nyB);   // refill B (row i+13, clamped)
        }
    }

    // --- per-wave reduction (fixed order, deterministic), no atomics ---
    for (int off = 32; off > 0; off >>= 1)
        acc += __shfl_down(acc, off, 64);
    if (lane == 0) partials[w_lin] = acc;   // batch-contiguous layout
}

__global__ __launch_bounds__(64) void ssim_reduce(const float* __restrict__ partials,
                                                  float* __restrict__ out) {
    const int b    = blockIdx.x;           // one wave per batch element
    const int lane = threadIdx.x & 63;
    float s = 0.f;
    for (int k = lane; k < WAVES_PER_BATCH; k += 64)   // 690, fixed order
        s += partials[b * WAVES_PER_BATCH + k];
    for (int off = 32; off > 0; off >>= 1)
        s += __shfl_down(s, off, 64);
    if (lane == 0)
        out[b] = (1.0f - s / NPIX_PER_BATCH) * 0.5f;
}

extern "C" void kernel_launch(void* const* d_in, const int* in_sizes, int n_in,
                              void* d_out, int out_size, void* d_ws, size_t ws_size,
                              hipStream_t stream) {
    const float* x = (const float*)d_in[0];
    const float* y = (const float*)d_in[1];
    float* out      = (float*)d_out;
    float* partials = (float*)d_ws;   // 5520 floats, fully overwritten each call

    ssim_main<<<NWAVES, 64, 0, stream>>>(x, y, partials);
    ssim_reduce<<<BATCH, 64, 0, stream>>>(partials, out);
}

// Round 19
// 27.333 us; speedup vs baseline: 1.0828x; 1.0828x over previous
//
#include <hip/hip_runtime.h>

#define WINDOW 11
#define H 512
#define W 512
#define OH 502            // H - WINDOW + 1 ; 502 = 2*251 exactly
#define OW 502
#define NCH 3
#define BATCH 8
#define RSTRIPE 2
#define NSTRIPES 251      // no tail: every stripe computes exactly 2 rows
#define WAVES_PER_IMG NSTRIPES                          // 251
#define NWAVES (BATCH * NCH * WAVES_PER_IMG)            // 6024
#define WAVES_PER_BATCH (NCH * WAVES_PER_IMG)           // 753
#define NXCD 8
#define CHUNK (NWAVES / NXCD)                           // 753 = one batch per XCD

#define NPIX_PER_BATCH (3.0f * 502.0f * 502.0f)   // 756012

typedef float v4f __attribute__((ext_vector_type(4)));  // packed f32 math
typedef float v2f __attribute__((ext_vector_type(2)));

// ---- gfx9 DPP inclusive wave scan (64 lanes), VALU-pipe only ----
template <int CTRL, int RM>
__device__ __forceinline__ float scan_step(float x) {
    int s = __builtin_amdgcn_update_dpp(0, __builtin_bit_cast(int, x),
                                        CTRL, RM, 0xf, false);
    return x + __builtin_bit_cast(float, s);
}
__device__ __forceinline__ float wave_iscan(float x) {
    x = scan_step<0x111, 0xf>(x);   // row_shr:1
    x = scan_step<0x112, 0xf>(x);   // row_shr:2
    x = scan_step<0x114, 0xf>(x);   // row_shr:4
    x = scan_step<0x118, 0xf>(x);   // row_shr:8
    x = scan_step<0x142, 0xa>(x);   // row_bcast:15 -> rows 1,3
    x = scan_step<0x143, 0xc>(x);   // row_bcast:31 -> rows 2,3
    return x;
}

__global__ __launch_bounds__(64) void ssim_main(const float* __restrict__ x,
                                                const float* __restrict__ y,
                                                float* __restrict__ partials) {
    const int lane = threadIdx.x & 63;

    // XCD-chunked bijective swizzle: one batch (3 images) per XCD.
    const int wg    = blockIdx.x;               // 0..6023, round-robins XCDs
    const int w_lin = (wg % NXCD) * CHUNK + wg / NXCD;

    const int img = w_lin / WAVES_PER_IMG;      // b*NCH + c
    const int rs  = w_lin % WAVES_PER_IMG;      // stripe
    const int r0  = 2 * rs;                     // first of 2 output rows

    // lane owns cols 8*lane .. 8*lane+7 (full row per wave, no halo)
    const int c0 = 8 * lane;
    const float* __restrict__ xc = x + (size_t)img * H * W + c0;
    const float* __restrict__ yc = y + (size_t)img * H * W + c0;

    // output-pair masks: pair j covers cols c0+2j, c0+2j+1; valid iff <= 501
    const bool mp0 = (c0     <= 500);
    const bool mp1 = (c0 + 2 <= 500);
    const bool mp2 = (c0 + 4 <= 500);
    const bool mp3 = (c0 + 6 <= 500);

    const int l1 = lane + 1, l2 = lane + 2;     // shuffle sources (wrap masked)

    // vertical 11-row column sums, 8 cols as two v4f halves per quantity
    v4f Qx0 = 0.f, Qx1 = 0.f, Qy0 = 0.f, Qy1 = 0.f;
    v4f Qz0 = 0.f, Qz1 = 0.f, Qw0 = 0.f, Qw1 = 0.f;
    v4f ka0, ka1, kb0, kb1;                     // kept row r0 (for the slide)

#define ACC(a0, a1, b0, b1) do {                                      \
        Qx0 += a0; Qx1 += a1;                                         \
        Qy0 += b0; Qy1 += b1;                                         \
        Qz0 += a0 * a0 + b0 * b0; Qz1 += a1 * a1 + b1 * b1;           \
        Qw0 += a0 * b0;           Qw1 += a1 * b1;                     \
    } while (0)

#pragma unroll
    for (int r = 0; r < WINDOW; ++r) {
        v4f a0 = *(const v4f*)(xc + (size_t)(r0 + r) * W);
        v4f a1 = *(const v4f*)(xc + (size_t)(r0 + r) * W + 4);
        v4f b0 = *(const v4f*)(yc + (size_t)(r0 + r) * W);
        v4f b1 = *(const v4f*)(yc + (size_t)(r0 + r) * W + 4);
        if (r == 0) { ka0 = a0; ka1 = a1; kb0 = b0; kb1 = b1; }
        ACC(a0, a1, b0, b1);
    }

    float acc = 0.f;

    // Per-quantity window sums: in-lane prefix + wave scan + prefix diffs.
    //   s[k] = global inclusive prefix through col 8l+k; E = prefix before lane
    //   W[k] = P_excl[8l+k+11] - P_excl[8l+k]
#define QWIN(Q0, Q1, w0, w1, w2, w3, w4, w5, w6, w7) do {             \
        float p0 = Q0.x, p1 = p0 + Q0.y, p2 = p1 + Q0.z;              \
        float p3 = p2 + Q0.w, p4 = p3 + Q1.x, p5 = p4 + Q1.y;         \
        float p6 = p5 + Q1.z, T = p6 + Q1.w;                          \
        float S = wave_iscan(T);                                      \
        float E = S - T;                                              \
        float s0 = E + p0, s1 = E + p1, s2 = E + p2, s3 = E + p3;     \
        float s4 = E + p4, s5 = E + p5, s6 = E + p6;                  \
        float r1s2 = __shfl(s2, l1, 64), r1s3 = __shfl(s3, l1, 64);   \
        float r1s4 = __shfl(s4, l1, 64), r1s5 = __shfl(s5, l1, 64);   \
        float r1s6 = __shfl(s6, l1, 64), r1s7 = __shfl(S,  l1, 64);   \
        float r2s0 = __shfl(s0, l2, 64), r2s1 = __shfl(s1, l2, 64);   \
        w0 = r1s2 - E;  w1 = r1s3 - s0;                               \
        w2 = r1s4 - s1; w3 = r1s5 - s2;                               \
        w4 = r1s6 - s3; w5 = r1s7 - s4;                               \
        w6 = r2s0 - s5; w7 = r2s1 - s6;                               \
    } while (0)

    // packed SSIM over one {even,odd} column pair
#define SSIM_PAIR(mask, WxP, WyP, WzP, WwP) do {                      \
        v2f mx  = WxP * (1.0f / 121.0f);                              \
        v2f my  = WyP * (1.0f / 121.0f);                              \
        v2f mxy = mx * my;                                            \
        v2f m2  = mx * mx + my * my;                                  \
        v2f cov = (WwP - 121.0f * mxy) * (1.0f / 120.0f);             \
        v2f vv  = (WzP - 121.0f * m2)  * (1.0f / 120.0f);             \
        v2f num = (2.0f * mxy + 1e-4f) * (2.0f * cov + 9e-4f);        \
        v2f den = (m2 + 1e-4f) * (vv + 9e-4f);                        \
        float r = num.x * __builtin_amdgcn_rcpf(den.x)                \
                + num.y * __builtin_amdgcn_rcpf(den.y);               \
        acc += (mask) ? r : 0.f;                                      \
    } while (0)

#define COMPUTE() do {                                                        \
        float wx0,wx1,wx2,wx3,wx4,wx5,wx6,wx7;                                \
        float wy0,wy1,wy2,wy3,wy4,wy5,wy6,wy7;                                \
        float wz0,wz1,wz2,wz3,wz4,wz5,wz6,wz7;                                \
        float ww0,ww1,ww2,ww3,ww4,ww5,ww6,ww7;                                \
        QWIN(Qx0,Qx1, wx0,wx1,wx2,wx3,wx4,wx5,wx6,wx7);                       \
        QWIN(Qy0,Qy1, wy0,wy1,wy2,wy3,wy4,wy5,wy6,wy7);                       \
        QWIN(Qz0,Qz1, wz0,wz1,wz2,wz3,wz4,wz5,wz6,wz7);                       \
        QWIN(Qw0,Qw1, ww0,ww1,ww2,ww3,ww4,ww5,ww6,ww7);                       \
        { v2f Wx={wx0,wx1}, Wy={wy0,wy1}, Wz={wz0,wz1}, Ww={ww0,ww1};         \
          SSIM_PAIR(mp0, Wx, Wy, Wz, Ww); }                                   \
        { v2f Wx={wx2,wx3}, Wy={wy2,wy3}, Wz={wz2,wz3}, Ww={ww2,ww3};         \
          SSIM_PAIR(mp1, Wx, Wy, Wz, Ww); }                                   \
        { v2f Wx={wx4,wx5}, Wy={wy4,wy5}, Wz={wz4,wz5}, Ww={ww4,ww5};         \
          SSIM_PAIR(mp2, Wx, Wy, Wz, Ww); }                                   \
        { v2f Wx={wx6,wx7}, Wy={wy6,wy7}, Wz={wz6,wz7}, Ww={ww6,ww7};         \
          SSIM_PAIR(mp3, Wx, Wy, Wz, Ww); }                                   \
    } while (0)

    COMPUTE();                                   // output row r0

    // slide: + row r0+11, - row r0 (kept in registers; no re-read)
    {
        v4f na0 = *(const v4f*)(xc + (size_t)(r0 + WINDOW) * W);
        v4f na1 = *(const v4f*)(xc + (size_t)(r0 + WINDOW) * W + 4);
        v4f nb0 = *(const v4f*)(yc + (size_t)(r0 + WINDOW) * W);
        v4f nb1 = *(const v4f*)(yc + (size_t)(r0 + WINDOW) * W + 4);
        Qx0 += na0 - ka0; Qx1 += na1 - ka1;
        Qy0 += nb0 - kb0; Qy1 += nb1 - kb1;
        Qz0 += na0 * na0 + nb0 * nb0 - ka0 * ka0 - kb0 * kb0;
        Qz1 += na1 * na1 + nb1 * nb1 - ka1 * ka1 - kb1 * kb1;
        Qw0 += na0 * nb0 - ka0 * kb0;
        Qw1 += na1 * nb1 - ka1 * kb1;
    }

    COMPUTE();                                   // output row r0+1

    // --- per-wave reduction (fixed order, deterministic), no atomics ---
    for (int off = 32; off > 0; off >>= 1)
        acc += __shfl_down(acc, off, 64);
    if (lane == 0) partials[w_lin] = acc;        // batch-contiguous layout
}

__global__ __launch_bounds__(64) void ssim_reduce(const float* __restrict__ partials,
                                                  float* __restrict__ out) {
    const int b    = blockIdx.x;           // one wave per batch element
    const int lane = threadIdx.x & 63;
    float s = 0.f;
    for (int k = lane; k < WAVES_PER_BATCH; k += 64)   // 753, fixed order
        s += partials[b * WAVES_PER_BATCH + k];
    for (int off = 32; off > 0; off >>= 1)
        s += __shfl_down(s, off, 64);
    if (lane == 0)
        out[b] = (1.0f - s / NPIX_PER_BATCH) * 0.5f;
}

extern "C" void kernel_launch(void* const* d_in, const int* in_sizes, int n_in,
                              void* d_out, int out_size, void* d_ws, size_t ws_size,
                              hipStream_t stream) {
    const float* x = (const float*)d_in[0];
    const float* y = (const float*)d_in[1];
    float* out      = (float*)d_out;
    float* partials = (float*)d_ws;   // 6024 floats, fully overwritten each call

    ssim_main<<<NWAVES, 64, 0, stream>>>(x, y, partials);
    ssim_reduce<<<BATCH, 64, 0, stream>>>(partials, out);
}